// Round 2
// baseline (4708.221 us; speedup 1.0000x reference)
//
#include <hip/hip_runtime.h>
#include <hip/hip_bf16.h>
#include <math.h>

// ---------------------------------------------------------------------------
// small utility kernels
// ---------------------------------------------------------------------------

__global__ void k_transpose(const float* __restrict__ W, float* __restrict__ WT,
                            int R, int C) {
  // W [R,C] -> WT [C,R]
  int idx = blockIdx.x * blockDim.x + threadIdx.x;
  if (idx < R * C) {
    int r = idx / C, c = idx % C;
    WT[(size_t)c * R + r] = W[idx];
  }
}

__global__ void k_fill1(float* __restrict__ p, int n) {
  int i = blockIdx.x * blockDim.x + threadIdx.x;
  if (i < n) p[i] = 1.0f;
}

__global__ void k_zero(float* __restrict__ p, size_t n) {
  size_t i = (size_t)blockIdx.x * blockDim.x + threadIdx.x;
  if (i < n) p[i] = 0.0f;
}

__global__ void k_scatter_deg(const int* __restrict__ dst, const float* __restrict__ ew,
                              float* __restrict__ deg, int E) {
  int e = blockIdx.x * blockDim.x + threadIdx.x;
  if (e < E) atomicAdd(&deg[dst[e]], ew[e]);
}

__global__ void k_rsqrt(float* __restrict__ p, int n) {
  int i = blockIdx.x * blockDim.x + threadIdx.x;
  if (i < n) p[i] = rsqrtf(p[i]);
}

__global__ void k_norm(const int* __restrict__ src, const int* __restrict__ dst,
                       const float* __restrict__ ew, const float* __restrict__ dinv,
                       float* __restrict__ nrm, int E) {
  int e = blockIdx.x * blockDim.x + threadIdx.x;
  if (e < E) nrm[e] = dinv[src[e]] * ew[e] * dinv[dst[e]];
}

// ---------------------------------------------------------------------------
// generic fp32 GEMM: C[M,Nc] = A[M,128] @ B[128,Nc] (+bias) (+relu)
// 64x64 tile, 256 threads, 4x4 micro-tile
// ---------------------------------------------------------------------------

template<bool RELU, bool BIAS>
__global__ __launch_bounds__(256) void k_gemm128(
    const float* __restrict__ A, const float* __restrict__ B,
    const float* __restrict__ bias, float* __restrict__ C, int M, int Nc) {
  __shared__ float As[64][36];   // padded rows
  __shared__ float Bs[32][64];
  int tid = threadIdx.x;
  int tx = tid & 15, ty = tid >> 4;
  int row0 = blockIdx.y * 64, col0 = blockIdx.x * 64;
  float acc[4][4] = {};

  for (int k0 = 0; k0 < 128; k0 += 32) {
#pragma unroll
    for (int i = 0; i < 2; ++i) {
      int f = tid + i * 256;
      int r = f >> 3, c4 = f & 7;
      int gr = row0 + r;
      float4 v = make_float4(0.f, 0.f, 0.f, 0.f);
      if (gr < M) v = *(const float4*)(A + (size_t)gr * 128 + k0 + c4 * 4);
      *(float4*)(&As[r][c4 * 4]) = v;
    }
#pragma unroll
    for (int i = 0; i < 2; ++i) {
      int f = tid + i * 256;
      int r = f >> 4, c4 = f & 15;
      int gc = col0 + c4 * 4;
      float4 v = make_float4(0.f, 0.f, 0.f, 0.f);
      if (gc + 3 < Nc) v = *(const float4*)(B + (size_t)(k0 + r) * Nc + gc);
      *(float4*)(&Bs[r][c4 * 4]) = v;
    }
    __syncthreads();
#pragma unroll
    for (int kk = 0; kk < 32; ++kk) {
      float4 b = *(float4*)(&Bs[kk][tx * 4]);
      float a0 = As[ty * 4 + 0][kk];
      float a1 = As[ty * 4 + 1][kk];
      float a2 = As[ty * 4 + 2][kk];
      float a3 = As[ty * 4 + 3][kk];
      acc[0][0] += a0 * b.x; acc[0][1] += a0 * b.y; acc[0][2] += a0 * b.z; acc[0][3] += a0 * b.w;
      acc[1][0] += a1 * b.x; acc[1][1] += a1 * b.y; acc[1][2] += a1 * b.z; acc[1][3] += a1 * b.w;
      acc[2][0] += a2 * b.x; acc[2][1] += a2 * b.y; acc[2][2] += a2 * b.z; acc[2][3] += a2 * b.w;
      acc[3][0] += a3 * b.x; acc[3][1] += a3 * b.y; acc[3][2] += a3 * b.z; acc[3][3] += a3 * b.w;
    }
    __syncthreads();
  }

#pragma unroll
  for (int i = 0; i < 4; ++i) {
    int gr = row0 + ty * 4 + i;
    if (gr >= M) continue;
#pragma unroll
    for (int j = 0; j < 4; ++j) {
      int gc = col0 + tx * 4 + j;
      if (gc >= Nc) continue;
      float v = acc[i][j];
      if (BIAS) v += bias[gc];
      if (RELU) v = fmaxf(v, 0.f);
      C[(size_t)gr * Nc + gc] = v;
    }
  }
}

// ---------------------------------------------------------------------------
// Fused GRU: gi = xh @ WihT + bih and gh = h @ WhhT + bhh computed in one
// kernel, then gate math. Block = 16 rows, 256 threads. Each block reads and
// writes ONLY its own 16 rows of h (barrier between read and write phases),
// so in-place h update is safe.
// ---------------------------------------------------------------------------

__device__ inline float gru1(float ir, float iz, float inn,
                             float hr, float hz, float hn, float h) {
  float r = 1.f / (1.f + expf(-(ir + hr)));
  float z = 1.f / (1.f + expf(-(iz + hz)));
  float n = tanhf(inn + r * hn);
  return (1.f - z) * n + z * h;
}

__global__ __launch_bounds__(256) void k_gru(
    const float* __restrict__ xh,    // [N,128]
    const float* h_in,               // [N,128] (may alias h_out)
    const float* __restrict__ WihT,  // [128,384]
    const float* __restrict__ WhhT,  // [128,384]
    const float* __restrict__ bih,   // [384]
    const float* __restrict__ bhh,   // [384]
    float* h_out) {
  __shared__ float Ax[16][17];
  __shared__ float Ah[16][17];
  __shared__ float Bi[16][384];
  __shared__ float Bh[16][384];
  int tid = threadIdx.x;
  int rl = tid >> 4, cg = tid & 15;
  size_t row = (size_t)blockIdx.x * 16 + rl;
  float4 acci[6] = {};  // gi accum over 384 cols (6 x float4 per thread)
  float4 acch[6] = {};  // gh accum

  for (int k0 = 0; k0 < 128; k0 += 16) {
    Ax[rl][cg] = xh[row * 128 + k0 + cg];
    Ah[rl][cg] = h_in[row * 128 + k0 + cg];
#pragma unroll
    for (int i = 0; i < 6; ++i) {
      int f = tid + i * 256;
      int r = f / 96, c4 = f % 96;
      *(float4*)(&Bi[r][c4 * 4]) =
          *(const float4*)(WihT + (size_t)(k0 + r) * 384 + c4 * 4);
      *(float4*)(&Bh[r][c4 * 4]) =
          *(const float4*)(WhhT + (size_t)(k0 + r) * 384 + c4 * 4);
    }
    __syncthreads();
#pragma unroll
    for (int kk = 0; kk < 16; ++kk) {
      float ax = Ax[rl][kk];
      float ah = Ah[rl][kk];
#pragma unroll
      for (int j = 0; j < 6; ++j) {
        float4 bi = *(float4*)(&Bi[kk][cg * 4 + 64 * j]);
        float4 bh = *(float4*)(&Bh[kk][cg * 4 + 64 * j]);
        acci[j].x += ax * bi.x; acci[j].y += ax * bi.y;
        acci[j].z += ax * bi.z; acci[j].w += ax * bi.w;
        acch[j].x += ah * bh.x; acch[j].y += ah * bh.y;
        acch[j].z += ah * bh.z; acch[j].w += ah * bh.w;
      }
    }
    __syncthreads();
  }

#pragma unroll
  for (int jj = 0; jj < 2; ++jj) {
    int ch = cg * 4 + 64 * jj;
    float4 ir = acci[jj], iz = acci[jj + 2], inn = acci[jj + 4];
    float4 hr = acch[jj], hz = acch[jj + 2], hn = acch[jj + 4];
    float4 bir = *(const float4*)(bih + ch);
    float4 biz = *(const float4*)(bih + 128 + ch);
    float4 bin = *(const float4*)(bih + 256 + ch);
    float4 br = *(const float4*)(bhh + ch);
    float4 bz = *(const float4*)(bhh + 128 + ch);
    float4 bn = *(const float4*)(bhh + 256 + ch);
    float4 hp = *(const float4*)(h_in + row * 128 + ch);
    float4 o;
    o.x = gru1(ir.x + bir.x, iz.x + biz.x, inn.x + bin.x,
               hr.x + br.x, hz.x + bz.x, hn.x + bn.x, hp.x);
    o.y = gru1(ir.y + bir.y, iz.y + biz.y, inn.y + bin.y,
               hr.y + br.y, hz.y + bz.y, hn.y + bn.y, hp.y);
    o.z = gru1(ir.z + bir.z, iz.z + biz.z, inn.z + bin.z,
               hr.z + br.z, hz.z + bz.z, hn.z + bn.z, hp.z);
    o.w = gru1(ir.w + bir.w, iz.w + biz.w, inn.w + bin.w,
               hr.w + br.w, hz.w + bz.w, hn.w + bn.w, hp.w);
    *(float4*)(h_out + row * 128 + ch) = o;
  }
}

// ---------------------------------------------------------------------------
// sparse aggregation: agg[dst] += xw[src] * norm   (atomic scatter, 2 edges/block)
// ---------------------------------------------------------------------------

__global__ __launch_bounds__(256) void k_edge_scatter(
    const int* __restrict__ src, const int* __restrict__ dst,
    const float* __restrict__ nrm, const float* __restrict__ xw,
    float* __restrict__ agg, int E) {
  int e = blockIdx.x * 2 + (threadIdx.x >> 7);
  if (e >= E) return;
  int c = threadIdx.x & 127;
  int s = src[e], d = dst[e];
  float w = nrm[e];
  atomicAdd(&agg[(size_t)d * 128 + c], xw[(size_t)s * 128 + c] * w);
}

// out[i,c] = relu(agg[i,c] + xw[i,c]*dinv[i]^2 + bias[c])   (self-loop folded in)
__global__ __launch_bounds__(256) void k_conv_fin(
    const float* __restrict__ agg, const float* __restrict__ xw,
    const float* __restrict__ dinv, const float* __restrict__ bias,
    float* __restrict__ out, int N) {
  size_t idx = (size_t)blockIdx.x * 256 + threadIdx.x;  // float4 index
  if (idx >= (size_t)N * 32) return;
  int node = (int)(idx >> 5);
  int c4 = (int)(idx & 31);
  float di = dinv[node];
  float sn = di * di;
  float4 a = *(const float4*)(agg + idx * 4);
  float4 w = *(const float4*)(xw + idx * 4);
  float4 b = *(const float4*)(bias + c4 * 4);
  float4 o;
  o.x = fmaxf(a.x + w.x * sn + b.x, 0.f);
  o.y = fmaxf(a.y + w.y * sn + b.y, 0.f);
  o.z = fmaxf(a.z + w.z * sn + b.z, 0.f);
  o.w = fmaxf(a.w + w.w * sn + b.w, 0.f);
  *(float4*)(out + idx * 4) = o;
}

// ---------------------------------------------------------------------------

extern "C" void kernel_launch(void* const* d_in, const int* in_sizes, int n_in,
                              void* d_out, int out_size, void* d_ws, size_t ws_size,
                              hipStream_t stream) {
  const float* x    = (const float*)d_in[0];
  const int*   ei   = (const int*)d_in[1];
  const float* ew   = (const float*)d_in[2];
  const float* h0   = (const float*)d_in[3];
  const float* linW = (const float*)d_in[4];
  const float* linB = (const float*)d_in[5];
  const float* convW= (const float*)d_in[6];
  const float* convB= (const float*)d_in[7];
  const float* Wih  = (const float*)d_in[8];
  const float* Whh  = (const float*)d_in[9];
  const float* bih  = (const float*)d_in[10];
  const float* bhh  = (const float*)d_in[11];
  const float* fcW  = (const float*)d_in[12];
  const float* fcB  = (const float*)d_in[13];

  int N = in_sizes[0] / 128;
  int E = in_sizes[1] / 2;
  const int* srcI = ei;
  const int* dstI = ei + E;

  // workspace layout (floats): total = E + N + 4*N*128 + 2*384*128
  //   = 1.6e6 + 1e5 + 51.2e6 + 98304  ~= 53.1e6 floats ~= 212 MB
  float* ws = (float*)d_ws;
  size_t off = 0;
  float* nrm  = ws + off; off += (size_t)E;
  float* dinv = ws + off; off += (size_t)N;
  float* xh   = ws + off; off += (size_t)N * 128;
  float* xw   = ws + off; off += (size_t)N * 128;
  float* agg  = ws + off; off += (size_t)N * 128;
  float* h    = ws + off; off += (size_t)N * 128;
  float* WihT = ws + off; off += 384 * 128;
  float* WhhT = ws + off; off += 384 * 128;

  // weight transposes (torch GRUCell: gi = x @ Wih^T)
  k_transpose<<<(384 * 128 + 255) / 256, 256, 0, stream>>>(Wih, WihT, 384, 128);
  k_transpose<<<(384 * 128 + 255) / 256, 256, 0, stream>>>(Whh, WhhT, 384, 128);

  // degree (self-loop weight 1 folded into init) -> dinv -> per-edge norm
  k_fill1<<<(N + 255) / 256, 256, 0, stream>>>(dinv, N);
  k_scatter_deg<<<(E + 255) / 256, 256, 0, stream>>>(dstI, ew, dinv, E);
  k_rsqrt<<<(N + 255) / 256, 256, 0, stream>>>(dinv, N);
  k_norm<<<(E + 255) / 256, 256, 0, stream>>>(srcI, dstI, ew, dinv, nrm, E);

  dim3 g128(2, (N + 63) / 64);
  dim3 g40(1, (N + 63) / 64);

  // xh = relu(x @ linW + linB)
  k_gemm128<true, true><<<g128, 256, 0, stream>>>(x, linW, linB, xh, N, 128);

  // GRU #1 (fused gi+gh GEMMs + gates)
  k_gru<<<(N + 15) / 16, 256, 0, stream>>>(xh, h0, WihT, WhhT, bih, bhh, h);

  for (int l = 0; l < 3; ++l) {
    // xw = xh @ convW[l]
    k_gemm128<false, false><<<g128, 256, 0, stream>>>(
        xh, convW + (size_t)l * 128 * 128, nullptr, xw, N, 128);
    // agg = scatter-add of normalized messages
    k_zero<<<(int)(((size_t)N * 128 + 255) / 256), 256, 0, stream>>>(agg, (size_t)N * 128);
    k_edge_scatter<<<(E + 1) / 2, 256, 0, stream>>>(srcI, dstI, nrm, xw, agg, E);
    // xh = relu(agg + xw*dinv^2 + convB[l])
    k_conv_fin<<<((N * 32) + 255) / 256, 256, 0, stream>>>(
        agg, xw, dinv, convB + (size_t)l * 128, xh, N);
    // GRU
    k_gru<<<(N + 15) / 16, 256, 0, stream>>>(xh, h, WihT, WhhT, bih, bhh, h);
  }

  // out = h @ fcW + fcB
  k_gemm128<false, true><<<g40, 256, 0, stream>>>(h, fcW, fcB, (float*)d_out, N, 40);
}

// Round 3
// 3543.669 us; speedup vs baseline: 1.3286x; 1.3286x over previous
//
#include <hip/hip_runtime.h>
#include <hip/hip_bf16.h>
#include <math.h>

// ---------------------------------------------------------------------------
// small utility kernels
// ---------------------------------------------------------------------------

__global__ void k_transpose(const float* __restrict__ W, float* __restrict__ WT,
                            int R, int C) {
  int idx = blockIdx.x * blockDim.x + threadIdx.x;
  if (idx < R * C) {
    int r = idx / C, c = idx % C;
    WT[(size_t)c * R + r] = W[idx];
  }
}

__global__ void k_fill1(float* __restrict__ p, int n) {
  int i = blockIdx.x * blockDim.x + threadIdx.x;
  if (i < n) p[i] = 1.0f;
}

__global__ void k_zero_i(int* __restrict__ p, int n) {
  int i = blockIdx.x * blockDim.x + threadIdx.x;
  if (i < n) p[i] = 0;
}

__global__ void k_scatter_deg(const int* __restrict__ dst, const float* __restrict__ ew,
                              float* __restrict__ deg, int E) {
  int e = blockIdx.x * blockDim.x + threadIdx.x;
  if (e < E) atomicAdd(&deg[dst[e]], ew[e]);
}

__global__ void k_count(const int* __restrict__ dst, int* __restrict__ cnt, int E) {
  int e = blockIdx.x * blockDim.x + threadIdx.x;
  if (e < E) atomicAdd(&cnt[dst[e]], 1);
}

__global__ void k_rsqrt(float* __restrict__ p, int n) {
  int i = blockIdx.x * blockDim.x + threadIdx.x;
  if (i < n) p[i] = rsqrtf(p[i]);
}

// ---------------------------------------------------------------------------
// hierarchical exclusive scan for rowptr (N up to 512*256 = 131072)
// ---------------------------------------------------------------------------

__global__ __launch_bounds__(256) void k_scan_block(
    const int* __restrict__ cnt, int* __restrict__ partial,
    int* __restrict__ bsum, int n) {
  __shared__ int s[256];
  int tid = threadIdx.x;
  int i = blockIdx.x * 256 + tid;
  s[tid] = (i < n) ? cnt[i] : 0;
  __syncthreads();
#pragma unroll
  for (int d = 1; d < 256; d <<= 1) {
    int t = (tid >= d) ? s[tid - d] : 0;
    __syncthreads();
    s[tid] += t;
    __syncthreads();
  }
  if (i < n) partial[i] = s[tid];        // inclusive within block
  if (tid == 255) bsum[blockIdx.x] = s[255];
}

__global__ __launch_bounds__(512) void k_scan_sums(int* __restrict__ bsum, int nb) {
  __shared__ int s[512];
  int tid = threadIdx.x;
  s[tid] = (tid < nb) ? bsum[tid] : 0;
  __syncthreads();
#pragma unroll
  for (int d = 1; d < 512; d <<= 1) {
    int t = (tid >= d) ? s[tid - d] : 0;
    __syncthreads();
    s[tid] += t;
    __syncthreads();
  }
  if (tid < nb) bsum[tid] = s[tid];      // inclusive scan of block sums
}

// rowptr[0]=0; rowptr[i+1] = partial[i] + (block offset); cursor[i]=rowptr[i]
__global__ __launch_bounds__(256) void k_scan_add(
    const int* __restrict__ partial, const int* __restrict__ bsum,
    int* __restrict__ rowptr, int* __restrict__ cursor, int n) {
  int i = blockIdx.x * 256 + threadIdx.x;
  if (i == 0) { rowptr[0] = 0; cursor[0] = 0; }
  if (i < n) {
    int v = partial[i] + (blockIdx.x > 0 ? bsum[blockIdx.x - 1] : 0);
    rowptr[i + 1] = v;
    if (i + 1 < n) cursor[i + 1] = v;
  }
}

// scatter edges into CSR slots (order within a row is arbitrary)
__global__ __launch_bounds__(256) void k_csr_fill(
    const int* __restrict__ src, const int* __restrict__ dst,
    const float* __restrict__ ew, const float* __restrict__ dinv,
    int* __restrict__ cursor, int* __restrict__ csr_src,
    float* __restrict__ csr_w, int E) {
  int e = blockIdx.x * 256 + threadIdx.x;
  if (e >= E) return;
  int s = src[e], d = dst[e];
  float w = dinv[s] * ew[e] * dinv[d];
  int pos = atomicAdd(&cursor[d], 1);
  csr_src[pos] = s;
  csr_w[pos] = w;
}

// ---------------------------------------------------------------------------
// generic fp32 GEMM: C[M,Nc] = A[M,128] @ B[128,Nc] (+bias) (+relu)
// ---------------------------------------------------------------------------

template<bool RELU, bool BIAS>
__global__ __launch_bounds__(256) void k_gemm128(
    const float* __restrict__ A, const float* __restrict__ B,
    const float* __restrict__ bias, float* __restrict__ C, int M, int Nc) {
  __shared__ float As[64][36];
  __shared__ float Bs[32][64];
  int tid = threadIdx.x;
  int tx = tid & 15, ty = tid >> 4;
  int row0 = blockIdx.y * 64, col0 = blockIdx.x * 64;
  float acc[4][4] = {};

  for (int k0 = 0; k0 < 128; k0 += 32) {
#pragma unroll
    for (int i = 0; i < 2; ++i) {
      int f = tid + i * 256;
      int r = f >> 3, c4 = f & 7;
      int gr = row0 + r;
      float4 v = make_float4(0.f, 0.f, 0.f, 0.f);
      if (gr < M) v = *(const float4*)(A + (size_t)gr * 128 + k0 + c4 * 4);
      *(float4*)(&As[r][c4 * 4]) = v;
    }
#pragma unroll
    for (int i = 0; i < 2; ++i) {
      int f = tid + i * 256;
      int r = f >> 4, c4 = f & 15;
      int gc = col0 + c4 * 4;
      float4 v = make_float4(0.f, 0.f, 0.f, 0.f);
      if (gc + 3 < Nc) v = *(const float4*)(B + (size_t)(k0 + r) * Nc + gc);
      *(float4*)(&Bs[r][c4 * 4]) = v;
    }
    __syncthreads();
#pragma unroll
    for (int kk = 0; kk < 32; ++kk) {
      float4 b = *(float4*)(&Bs[kk][tx * 4]);
      float a0 = As[ty * 4 + 0][kk];
      float a1 = As[ty * 4 + 1][kk];
      float a2 = As[ty * 4 + 2][kk];
      float a3 = As[ty * 4 + 3][kk];
      acc[0][0] += a0 * b.x; acc[0][1] += a0 * b.y; acc[0][2] += a0 * b.z; acc[0][3] += a0 * b.w;
      acc[1][0] += a1 * b.x; acc[1][1] += a1 * b.y; acc[1][2] += a1 * b.z; acc[1][3] += a1 * b.w;
      acc[2][0] += a2 * b.x; acc[2][1] += a2 * b.y; acc[2][2] += a2 * b.z; acc[2][3] += a2 * b.w;
      acc[3][0] += a3 * b.x; acc[3][1] += a3 * b.y; acc[3][2] += a3 * b.z; acc[3][3] += a3 * b.w;
    }
    __syncthreads();
  }

#pragma unroll
  for (int i = 0; i < 4; ++i) {
    int gr = row0 + ty * 4 + i;
    if (gr >= M) continue;
#pragma unroll
    for (int j = 0; j < 4; ++j) {
      int gc = col0 + tx * 4 + j;
      if (gc >= Nc) continue;
      float v = acc[i][j];
      if (BIAS) v += bias[gc];
      if (RELU) v = fmaxf(v, 0.f);
      C[(size_t)gr * Nc + gc] = v;
    }
  }
}

// ---------------------------------------------------------------------------
// Fused GRU (gi and gh GEMMs + gate math). Block = 16 rows; in-place h safe.
// ---------------------------------------------------------------------------

__device__ inline float gru1(float ir, float iz, float inn,
                             float hr, float hz, float hn, float h) {
  float r = 1.f / (1.f + expf(-(ir + hr)));
  float z = 1.f / (1.f + expf(-(iz + hz)));
  float n = tanhf(inn + r * hn);
  return (1.f - z) * n + z * h;
}

__global__ __launch_bounds__(256) void k_gru(
    const float* __restrict__ xh, const float* h_in,
    const float* __restrict__ WihT, const float* __restrict__ WhhT,
    const float* __restrict__ bih, const float* __restrict__ bhh,
    float* h_out) {
  __shared__ float Ax[16][17];
  __shared__ float Ah[16][17];
  __shared__ float Bi[16][384];
  __shared__ float Bh[16][384];
  int tid = threadIdx.x;
  int rl = tid >> 4, cg = tid & 15;
  size_t row = (size_t)blockIdx.x * 16 + rl;
  float4 acci[6] = {};
  float4 acch[6] = {};

  for (int k0 = 0; k0 < 128; k0 += 16) {
    Ax[rl][cg] = xh[row * 128 + k0 + cg];
    Ah[rl][cg] = h_in[row * 128 + k0 + cg];
#pragma unroll
    for (int i = 0; i < 6; ++i) {
      int f = tid + i * 256;
      int r = f / 96, c4 = f % 96;
      *(float4*)(&Bi[r][c4 * 4]) =
          *(const float4*)(WihT + (size_t)(k0 + r) * 384 + c4 * 4);
      *(float4*)(&Bh[r][c4 * 4]) =
          *(const float4*)(WhhT + (size_t)(k0 + r) * 384 + c4 * 4);
    }
    __syncthreads();
#pragma unroll
    for (int kk = 0; kk < 16; ++kk) {
      float ax = Ax[rl][kk];
      float ah = Ah[rl][kk];
#pragma unroll
      for (int j = 0; j < 6; ++j) {
        float4 bi = *(float4*)(&Bi[kk][cg * 4 + 64 * j]);
        float4 bh = *(float4*)(&Bh[kk][cg * 4 + 64 * j]);
        acci[j].x += ax * bi.x; acci[j].y += ax * bi.y;
        acci[j].z += ax * bi.z; acci[j].w += ax * bi.w;
        acch[j].x += ah * bh.x; acch[j].y += ah * bh.y;
        acch[j].z += ah * bh.z; acch[j].w += ah * bh.w;
      }
    }
    __syncthreads();
  }

#pragma unroll
  for (int jj = 0; jj < 2; ++jj) {
    int ch = cg * 4 + 64 * jj;
    float4 ir = acci[jj], iz = acci[jj + 2], inn = acci[jj + 4];
    float4 hr = acch[jj], hz = acch[jj + 2], hn = acch[jj + 4];
    float4 bir = *(const float4*)(bih + ch);
    float4 biz = *(const float4*)(bih + 128 + ch);
    float4 bin = *(const float4*)(bih + 256 + ch);
    float4 br = *(const float4*)(bhh + ch);
    float4 bz = *(const float4*)(bhh + 128 + ch);
    float4 bn = *(const float4*)(bhh + 256 + ch);
    float4 hp = *(const float4*)(h_in + row * 128 + ch);
    float4 o;
    o.x = gru1(ir.x + bir.x, iz.x + biz.x, inn.x + bin.x,
               hr.x + br.x, hz.x + bz.x, hn.x + bn.x, hp.x);
    o.y = gru1(ir.y + bir.y, iz.y + biz.y, inn.y + bin.y,
               hr.y + br.y, hz.y + bz.y, hn.y + bn.y, hp.y);
    o.z = gru1(ir.z + bir.z, iz.z + biz.z, inn.z + bin.z,
               hr.z + br.z, hz.z + bz.z, hn.z + bn.z, hp.z);
    o.w = gru1(ir.w + bir.w, iz.w + biz.w, inn.w + bin.w,
               hr.w + br.w, hz.w + bz.w, hn.w + bn.w, hp.w);
    *(float4*)(h_out + row * 128 + ch) = o;
  }
}

// ---------------------------------------------------------------------------
// CSR gather aggregation, fused finalize:
//   xh[i,c] = relu( sum_k xw[csr_src[k],c]*csr_w[k] + xw[i,c]*dinv[i]^2 + b[c] )
// 2 nodes per 256-thread block; each output written exactly once.
// ---------------------------------------------------------------------------

__global__ __launch_bounds__(256) void k_gather(
    const int* __restrict__ rowptr, const int* __restrict__ csr_src,
    const float* __restrict__ csr_w, const float* __restrict__ xw,
    const float* __restrict__ dinv, const float* __restrict__ bias,
    float* __restrict__ out, int N) {
  int node = blockIdx.x * 2 + (threadIdx.x >> 7);
  int c = threadIdx.x & 127;
  if (node >= N) return;
  int beg = rowptr[node], end = rowptr[node + 1];
  float acc = 0.f;
  for (int k = beg; k < end; ++k) {
    int s = csr_src[k];
    float w = csr_w[k];
    acc += xw[(size_t)s * 128 + c] * w;
  }
  float di = dinv[node];
  float v = acc + xw[(size_t)node * 128 + c] * (di * di) + bias[c];
  out[(size_t)node * 128 + c] = fmaxf(v, 0.f);
}

// ---------------------------------------------------------------------------

extern "C" void kernel_launch(void* const* d_in, const int* in_sizes, int n_in,
                              void* d_out, int out_size, void* d_ws, size_t ws_size,
                              hipStream_t stream) {
  const float* x    = (const float*)d_in[0];
  const int*   ei   = (const int*)d_in[1];
  const float* ew   = (const float*)d_in[2];
  const float* h0   = (const float*)d_in[3];
  const float* linW = (const float*)d_in[4];
  const float* linB = (const float*)d_in[5];
  const float* convW= (const float*)d_in[6];
  const float* convB= (const float*)d_in[7];
  const float* Wih  = (const float*)d_in[8];
  const float* Whh  = (const float*)d_in[9];
  const float* bih  = (const float*)d_in[10];
  const float* bhh  = (const float*)d_in[11];
  const float* fcW  = (const float*)d_in[12];
  const float* fcB  = (const float*)d_in[13];

  int N = in_sizes[0] / 128;
  int E = in_sizes[1] / 2;
  const int* srcI = ei;
  const int* dstI = ei + E;
  int nb = (N + 255) / 256;   // scan blocks; requires nb <= 512 (N <= 131072)

  // workspace layout. floats+ints, total ~168 MB.
  float* ws = (float*)d_ws;
  size_t off = 0;
  float* dinv   = ws + off; off += (size_t)N;
  float* csr_w  = ws + off; off += (size_t)E;
  float* xh     = ws + off; off += (size_t)N * 128;
  float* xw     = ws + off; off += (size_t)N * 128;
  float* h      = ws + off; off += (size_t)N * 128;
  float* WihT   = ws + off; off += 384 * 128;
  float* WhhT   = ws + off; off += 384 * 128;
  int* iws = (int*)(ws + off);
  size_t ioff = 0;
  int* cnt     = iws + ioff; ioff += (size_t)N;
  int* partial = iws + ioff; ioff += (size_t)N;
  int* bsum    = iws + ioff; ioff += 512;
  int* rowptr  = iws + ioff; ioff += (size_t)N + 1;
  int* cursor  = iws + ioff; ioff += (size_t)N;
  int* csr_src = iws + ioff; ioff += (size_t)E;

  // weight transposes (torch GRUCell: gi = x @ Wih^T)
  k_transpose<<<(384 * 128 + 255) / 256, 256, 0, stream>>>(Wih, WihT, 384, 128);
  k_transpose<<<(384 * 128 + 255) / 256, 256, 0, stream>>>(Whh, WhhT, 384, 128);

  // weighted degree (with self-loop weight 1) -> dinv
  k_fill1<<<nb, 256, 0, stream>>>(dinv, N);
  k_scatter_deg<<<(E + 255) / 256, 256, 0, stream>>>(dstI, ew, dinv, E);
  k_rsqrt<<<nb, 256, 0, stream>>>(dinv, N);

  // CSR build: count -> scan -> fill (self-loops NOT in CSR; folded in gather)
  k_zero_i<<<nb, 256, 0, stream>>>(cnt, N);
  k_count<<<(E + 255) / 256, 256, 0, stream>>>(dstI, cnt, E);
  k_scan_block<<<nb, 256, 0, stream>>>(cnt, partial, bsum, N);
  k_scan_sums<<<1, 512, 0, stream>>>(bsum, nb);
  k_scan_add<<<nb, 256, 0, stream>>>(partial, bsum, rowptr, cursor, N);
  k_csr_fill<<<(E + 255) / 256, 256, 0, stream>>>(
      srcI, dstI, ew, dinv, cursor, csr_src, csr_w, E);

  dim3 g128(2, (N + 63) / 64);
  dim3 g40(1, (N + 63) / 64);

  // xh = relu(x @ linW + linB)
  k_gemm128<true, true><<<g128, 256, 0, stream>>>(x, linW, linB, xh, N, 128);

  // GRU #1
  k_gru<<<(N + 15) / 16, 256, 0, stream>>>(xh, h0, WihT, WhhT, bih, bhh, h);

  for (int l = 0; l < 3; ++l) {
    // xw = xh @ convW[l]
    k_gemm128<false, false><<<g128, 256, 0, stream>>>(
        xh, convW + (size_t)l * 128 * 128, nullptr, xw, N, 128);
    // xh = relu(gather(xw) + self-loop + bias)
    k_gather<<<(N + 1) / 2, 256, 0, stream>>>(
        rowptr, csr_src, csr_w, xw, dinv, convB + (size_t)l * 128, xh, N);
    // GRU
    k_gru<<<(N + 15) / 16, 256, 0, stream>>>(xh, h, WihT, WhhT, bih, bhh, h);
  }

  // out = h @ fcW + fcB
  k_gemm128<false, true><<<g40, 256, 0, stream>>>(h, fcW, fcB, (float*)d_out, N, 40);
}

// Round 4
// 1671.716 us; speedup vs baseline: 2.8164x; 2.1198x over previous
//
#include <hip/hip_runtime.h>
#include <hip/hip_bf16.h>
#include <math.h>

typedef __attribute__((ext_vector_type(8))) short bf8_t;   // 8 x bf16 (4 VGPRs)
typedef __attribute__((ext_vector_type(4))) float f4_t;    // MFMA accumulator
typedef __attribute__((ext_vector_type(8))) unsigned short us8_t;

__device__ inline unsigned short f2bf(float f) {
  union { float f; unsigned u; } x; x.f = f;
  unsigned r = x.u + 0x7FFF + ((x.u >> 16) & 1);   // RNE
  return (unsigned short)(r >> 16);
}
__device__ inline float bf2f(unsigned short b) {
  union { unsigned u; float f; } x; x.u = ((unsigned)b) << 16;
  return x.f;
}

// ---------------------------------------------------------------------------
// small utility kernels
// ---------------------------------------------------------------------------

__global__ void k_fill1(float* __restrict__ p, int n) {
  int i = blockIdx.x * blockDim.x + threadIdx.x;
  if (i < n) p[i] = 1.0f;
}

__global__ void k_zero_i(int* __restrict__ p, int n) {
  int i = blockIdx.x * blockDim.x + threadIdx.x;
  if (i < n) p[i] = 0;
}

__global__ void k_scatter_deg(const int* __restrict__ dst, const float* __restrict__ ew,
                              float* __restrict__ deg, int E) {
  int e = blockIdx.x * blockDim.x + threadIdx.x;
  if (e < E) atomicAdd(&deg[dst[e]], ew[e]);
}

__global__ void k_count(const int* __restrict__ dst, int* __restrict__ cnt, int E) {
  int e = blockIdx.x * blockDim.x + threadIdx.x;
  if (e < E) atomicAdd(&cnt[dst[e]], 1);
}

__global__ void k_rsqrt(float* __restrict__ p, int n) {
  int i = blockIdx.x * blockDim.x + threadIdx.x;
  if (i < n) p[i] = rsqrtf(p[i]);
}

// fp32 -> bf16 bulk convert (n multiple of 8)
__global__ void k_f2bf(const float* __restrict__ in, unsigned short* __restrict__ out,
                       size_t n8) {
  size_t i = (size_t)blockIdx.x * blockDim.x + threadIdx.x;
  if (i >= n8) return;
  const float4* p = (const float4*)(in + i * 8);
  float4 a = p[0], b = p[1];
  us8_t v;
  v[0] = f2bf(a.x); v[1] = f2bf(a.y); v[2] = f2bf(a.z); v[3] = f2bf(a.w);
  v[4] = f2bf(b.x); v[5] = f2bf(b.y); v[6] = f2bf(b.z); v[7] = f2bf(b.w);
  *(us8_t*)(out + i * 8) = v;
}

// pack weight matrix into MFMA B-fragment order (16x16x32 bf16).
// B[k][n] = trans ? W[n*ldw+k] : W[k*ldw+n]
// fragment (n0,k0): lane holds B[k0*32+(lane>>4)*8+j][n0*16+(lane&15)], j=0..7
// out offset = ((n0*(K/32)+k0)*64 + lane)*8
__global__ void k_packB(const float* __restrict__ W, unsigned short* __restrict__ out,
                        int K, int Ncols, int ldw, int trans) {
  int idx = blockIdx.x * 256 + threadIdx.x;
  int total = (Ncols / 16) * (K / 32) * 64;
  if (idx >= total) return;
  int lane = idx & 63;
  int frag = idx >> 6;
  int kt = K / 32;
  int k0 = frag % kt;
  int n0 = frag / kt;
  int n = n0 * 16 + (lane & 15);
  int kbase = k0 * 32 + (lane >> 4) * 8;
  us8_t v;
#pragma unroll
  for (int j = 0; j < 8; ++j) {
    int k = kbase + j;
    float f = trans ? W[(size_t)n * ldw + k] : W[(size_t)k * ldw + n];
    v[j] = f2bf(f);
  }
  *(us8_t*)(out + (size_t)idx * 8) = v;
}

// ---------------------------------------------------------------------------
// hierarchical scan for rowptr (N up to 512*256 = 131072)
// ---------------------------------------------------------------------------

__global__ __launch_bounds__(256) void k_scan_block(
    const int* __restrict__ cnt, int* __restrict__ partial,
    int* __restrict__ bsum, int n) {
  __shared__ int s[256];
  int tid = threadIdx.x;
  int i = blockIdx.x * 256 + tid;
  s[tid] = (i < n) ? cnt[i] : 0;
  __syncthreads();
#pragma unroll
  for (int d = 1; d < 256; d <<= 1) {
    int t = (tid >= d) ? s[tid - d] : 0;
    __syncthreads();
    s[tid] += t;
    __syncthreads();
  }
  if (i < n) partial[i] = s[tid];
  if (tid == 255) bsum[blockIdx.x] = s[255];
}

__global__ __launch_bounds__(512) void k_scan_sums(int* __restrict__ bsum, int nb) {
  __shared__ int s[512];
  int tid = threadIdx.x;
  s[tid] = (tid < nb) ? bsum[tid] : 0;
  __syncthreads();
#pragma unroll
  for (int d = 1; d < 512; d <<= 1) {
    int t = (tid >= d) ? s[tid - d] : 0;
    __syncthreads();
    s[tid] += t;
    __syncthreads();
  }
  if (tid < nb) bsum[tid] = s[tid];
}

__global__ __launch_bounds__(256) void k_scan_add(
    const int* __restrict__ partial, const int* __restrict__ bsum,
    int* __restrict__ rowptr, int* __restrict__ cursor, int n) {
  int i = blockIdx.x * 256 + threadIdx.x;
  if (i == 0) { rowptr[0] = 0; cursor[0] = 0; }
  if (i < n) {
    int v = partial[i] + (blockIdx.x > 0 ? bsum[blockIdx.x - 1] : 0);
    rowptr[i + 1] = v;
    if (i + 1 < n) cursor[i + 1] = v;
  }
}

__global__ __launch_bounds__(256) void k_csr_fill(
    const int* __restrict__ src, const int* __restrict__ dst,
    const float* __restrict__ ew, const float* __restrict__ dinv,
    int* __restrict__ cursor, int* __restrict__ csr_src,
    float* __restrict__ csr_w, int E) {
  int e = blockIdx.x * 256 + threadIdx.x;
  if (e >= E) return;
  int s = src[e], d = dst[e];
  float w = dinv[s] * ew[e] * dinv[d];
  int pos = atomicAdd(&cursor[d], 1);
  csr_src[pos] = s;
  csr_w[pos] = w;
}

// ---------------------------------------------------------------------------
// MFMA GEMM: C[M,128] = A[M,128] @ B[128,128] (+bias)(+relu), bf16 in/out.
// 4 waves/block, 16 rows/wave. B pre-packed in fragment order.
// ---------------------------------------------------------------------------

template<bool RELU, bool BIAS>
__global__ __launch_bounds__(256) void k_mfma_gemm(
    const unsigned short* __restrict__ A, const unsigned short* __restrict__ Bp,
    const float* __restrict__ bias, unsigned short* __restrict__ C, int M) {
  int wave = threadIdx.x >> 6, lane = threadIdx.x & 63;
  int row0 = (blockIdx.x * 4 + wave) * 16;
  if (row0 >= M) return;
  int m = lane & 15, q = lane >> 4;
  int arow = row0 + m; if (arow >= M) arow = M - 1;
  bf8_t a[4];
#pragma unroll
  for (int k0 = 0; k0 < 4; ++k0)
    a[k0] = *(const bf8_t*)(A + (size_t)arow * 128 + k0 * 32 + q * 8);
#pragma unroll
  for (int n0 = 0; n0 < 8; ++n0) {
    f4_t acc = {};
#pragma unroll
    for (int k0 = 0; k0 < 4; ++k0) {
      bf8_t b = *(const bf8_t*)(Bp + ((size_t)(n0 * 4 + k0) * 64 + lane) * 8);
      acc = __builtin_amdgcn_mfma_f32_16x16x32_bf16(a[k0], b, acc, 0, 0, 0);
    }
    int col = n0 * 16 + m;
    float bs = BIAS ? bias[col] : 0.f;
#pragma unroll
    for (int r = 0; r < 4; ++r) {
      int grow = row0 + q * 4 + r;
      if (grow < M) {
        float v = acc[r] + bs;
        if (RELU) v = fmaxf(v, 0.f);
        C[(size_t)grow * 128 + col] = f2bf(v);
      }
    }
  }
}

// ---------------------------------------------------------------------------
// Fused MFMA GRU. Wave owns 16 rows. gi = xh@WihT+bih, gh = h@WhhT+bhh via
// MFMA (bf16 inputs, fp32 acc), gates in fp32, h updated (h_in may == h_out;
// each row touched by exactly one wave, all reads precede writes in-wave).
// ---------------------------------------------------------------------------

__global__ __launch_bounds__(256) void k_gru_mfma(
    const unsigned short* __restrict__ xh,  // [M,128] bf16
    const float* h_in,                      // [M,128] fp32
    float* h_out,                           // [M,128] fp32 (may alias h_in)
    const unsigned short* __restrict__ Bi,  // packed WihT (K=128, Ncols=384)
    const unsigned short* __restrict__ Bh,  // packed WhhT
    const float* __restrict__ bih, const float* __restrict__ bhh, int M) {
  int wave = threadIdx.x >> 6, lane = threadIdx.x & 63;
  int row0 = (blockIdx.x * 4 + wave) * 16;
  if (row0 >= M) return;
  int m = lane & 15, q = lane >> 4;
  int arow = row0 + m; if (arow >= M) arow = M - 1;

  bf8_t ax[4], ah[4];
#pragma unroll
  for (int k0 = 0; k0 < 4; ++k0) {
    ax[k0] = *(const bf8_t*)(xh + (size_t)arow * 128 + k0 * 32 + q * 8);
    const float* hp = h_in + (size_t)arow * 128 + k0 * 32 + q * 8;
    float4 h0 = *(const float4*)hp;
    float4 h1 = *(const float4*)(hp + 4);
    bf8_t t;
    t[0] = (short)f2bf(h0.x); t[1] = (short)f2bf(h0.y);
    t[2] = (short)f2bf(h0.z); t[3] = (short)f2bf(h0.w);
    t[4] = (short)f2bf(h1.x); t[5] = (short)f2bf(h1.y);
    t[6] = (short)f2bf(h1.z); t[7] = (short)f2bf(h1.w);
    ah[k0] = t;
  }

  for (int g = 0; g < 8; ++g) {
    f4_t air = {}, aiz = {}, ain = {}, ahr = {}, ahz = {}, ahn = {};
#pragma unroll
    for (int k0 = 0; k0 < 4; ++k0) {
      bf8_t br = *(const bf8_t*)(Bi + ((size_t)((g     ) * 4 + k0) * 64 + lane) * 8);
      bf8_t bz = *(const bf8_t*)(Bi + ((size_t)((g +  8) * 4 + k0) * 64 + lane) * 8);
      bf8_t bn = *(const bf8_t*)(Bi + ((size_t)((g + 16) * 4 + k0) * 64 + lane) * 8);
      air = __builtin_amdgcn_mfma_f32_16x16x32_bf16(ax[k0], br, air, 0, 0, 0);
      aiz = __builtin_amdgcn_mfma_f32_16x16x32_bf16(ax[k0], bz, aiz, 0, 0, 0);
      ain = __builtin_amdgcn_mfma_f32_16x16x32_bf16(ax[k0], bn, ain, 0, 0, 0);
      bf8_t cr = *(const bf8_t*)(Bh + ((size_t)((g     ) * 4 + k0) * 64 + lane) * 8);
      bf8_t cz = *(const bf8_t*)(Bh + ((size_t)((g +  8) * 4 + k0) * 64 + lane) * 8);
      bf8_t cn = *(const bf8_t*)(Bh + ((size_t)((g + 16) * 4 + k0) * 64 + lane) * 8);
      ahr = __builtin_amdgcn_mfma_f32_16x16x32_bf16(ah[k0], cr, ahr, 0, 0, 0);
      ahz = __builtin_amdgcn_mfma_f32_16x16x32_bf16(ah[k0], cz, ahz, 0, 0, 0);
      ahn = __builtin_amdgcn_mfma_f32_16x16x32_bf16(ah[k0], cn, ahn, 0, 0, 0);
    }
    int col = g * 16 + m;
    float bir_ = bih[col], biz_ = bih[col + 128], bin_ = bih[col + 256];
    float bhr_ = bhh[col], bhz_ = bhh[col + 128], bhn_ = bhh[col + 256];
#pragma unroll
    for (int r = 0; r < 4; ++r) {
      int grow = row0 + q * 4 + r;
      if (grow < M) {
        float hprev = h_in[(size_t)grow * 128 + col];
        float rr = 1.f / (1.f + expf(-(air[r] + bir_ + ahr[r] + bhr_)));
        float zz = 1.f / (1.f + expf(-(aiz[r] + biz_ + ahz[r] + bhz_)));
        float nn = tanhf(ain[r] + bin_ + rr * (ahn[r] + bhn_));
        h_out[(size_t)grow * 128 + col] = (1.f - zz) * nn + zz * hprev;
      }
    }
  }
}

// ---------------------------------------------------------------------------
// fp32 GEMM (kept for the final fc layer): C[M,Nc] = A[M,128] @ B[128,Nc] + b
// ---------------------------------------------------------------------------

template<bool RELU, bool BIAS>
__global__ __launch_bounds__(256) void k_gemm128(
    const float* __restrict__ A, const float* __restrict__ B,
    const float* __restrict__ bias, float* __restrict__ C, int M, int Nc) {
  __shared__ float As[64][36];
  __shared__ float Bs[32][64];
  int tid = threadIdx.x;
  int tx = tid & 15, ty = tid >> 4;
  int row0 = blockIdx.y * 64, col0 = blockIdx.x * 64;
  float acc[4][4] = {};

  for (int k0 = 0; k0 < 128; k0 += 32) {
#pragma unroll
    for (int i = 0; i < 2; ++i) {
      int f = tid + i * 256;
      int r = f >> 3, c4 = f & 7;
      int gr = row0 + r;
      float4 v = make_float4(0.f, 0.f, 0.f, 0.f);
      if (gr < M) v = *(const float4*)(A + (size_t)gr * 128 + k0 + c4 * 4);
      *(float4*)(&As[r][c4 * 4]) = v;
    }
#pragma unroll
    for (int i = 0; i < 2; ++i) {
      int f = tid + i * 256;
      int r = f >> 4, c4 = f & 15;
      int gc = col0 + c4 * 4;
      float4 v = make_float4(0.f, 0.f, 0.f, 0.f);
      if (gc + 3 < Nc) v = *(const float4*)(B + (size_t)(k0 + r) * Nc + gc);
      *(float4*)(&Bs[r][c4 * 4]) = v;
    }
    __syncthreads();
#pragma unroll
    for (int kk = 0; kk < 32; ++kk) {
      float4 b = *(float4*)(&Bs[kk][tx * 4]);
      float a0 = As[ty * 4 + 0][kk];
      float a1 = As[ty * 4 + 1][kk];
      float a2 = As[ty * 4 + 2][kk];
      float a3 = As[ty * 4 + 3][kk];
      acc[0][0] += a0 * b.x; acc[0][1] += a0 * b.y; acc[0][2] += a0 * b.z; acc[0][3] += a0 * b.w;
      acc[1][0] += a1 * b.x; acc[1][1] += a1 * b.y; acc[1][2] += a1 * b.z; acc[1][3] += a1 * b.w;
      acc[2][0] += a2 * b.x; acc[2][1] += a2 * b.y; acc[2][2] += a2 * b.z; acc[2][3] += a2 * b.w;
      acc[3][0] += a3 * b.x; acc[3][1] += a3 * b.y; acc[3][2] += a3 * b.z; acc[3][3] += a3 * b.w;
    }
    __syncthreads();
  }

#pragma unroll
  for (int i = 0; i < 4; ++i) {
    int gr = row0 + ty * 4 + i;
    if (gr >= M) continue;
#pragma unroll
    for (int j = 0; j < 4; ++j) {
      int gc = col0 + tx * 4 + j;
      if (gc >= Nc) continue;
      float v = acc[i][j];
      if (BIAS) v += bias[gc];
      if (RELU) v = fmaxf(v, 0.f);
      C[(size_t)gr * Nc + gc] = v;
    }
  }
}

// ---------------------------------------------------------------------------
// CSR gather aggregation (bf16 features), fused self-loop + bias + relu
// ---------------------------------------------------------------------------

__global__ __launch_bounds__(256) void k_gather(
    const int* __restrict__ rowptr, const int* __restrict__ csr_src,
    const float* __restrict__ csr_w, const unsigned short* __restrict__ xw,
    const float* __restrict__ dinv, const float* __restrict__ bias,
    unsigned short* __restrict__ out, int N) {
  int node = blockIdx.x * 2 + (threadIdx.x >> 7);
  int c = threadIdx.x & 127;
  if (node >= N) return;
  int beg = rowptr[node], end = rowptr[node + 1];
  float acc = 0.f;
  for (int k = beg; k < end; ++k) {
    int s = csr_src[k];
    float w = csr_w[k];
    acc += bf2f(xw[(size_t)s * 128 + c]) * w;
  }
  float di = dinv[node];
  float v = acc + bf2f(xw[(size_t)node * 128 + c]) * (di * di) + bias[c];
  out[(size_t)node * 128 + c] = f2bf(fmaxf(v, 0.f));
}

// ---------------------------------------------------------------------------

extern "C" void kernel_launch(void* const* d_in, const int* in_sizes, int n_in,
                              void* d_out, int out_size, void* d_ws, size_t ws_size,
                              hipStream_t stream) {
  const float* x    = (const float*)d_in[0];
  const int*   ei   = (const int*)d_in[1];
  const float* ew   = (const float*)d_in[2];
  const float* h0   = (const float*)d_in[3];
  const float* linW = (const float*)d_in[4];
  const float* linB = (const float*)d_in[5];
  const float* convW= (const float*)d_in[6];
  const float* convB= (const float*)d_in[7];
  const float* Wih  = (const float*)d_in[8];
  const float* Whh  = (const float*)d_in[9];
  const float* bih  = (const float*)d_in[10];
  const float* bhh  = (const float*)d_in[11];
  const float* fcW  = (const float*)d_in[12];
  const float* fcB  = (const float*)d_in[13];

  int N = in_sizes[0] / 128;
  int E = in_sizes[1] / 2;
  const int* srcI = ei;
  const int* dstI = ei + E;
  int nb = (N + 255) / 256;

  // ---- workspace layout ----
  float* ws = (float*)d_ws;
  size_t off = 0;
  float* dinv  = ws + off; off += (size_t)N;
  float* csr_w = ws + off; off += (size_t)E;
  float* h     = ws + off; off += (size_t)N * 128;
  int* iws = (int*)(ws + off);
  size_t ioff = 0;
  int* cnt     = iws + ioff; ioff += (size_t)N;
  int* partial = iws + ioff; ioff += (size_t)N;
  int* bsum    = iws + ioff; ioff += 512;
  int* rowptr  = iws + ioff; ioff += (size_t)N + 1;
  int* cursor  = iws + ioff; ioff += (size_t)N;
  int* csr_src = iws + ioff; ioff += (size_t)E;
  unsigned short* usws = (unsigned short*)(iws + ioff);
  size_t uoff = 0;
  unsigned short* x_bf   = usws + uoff; uoff += (size_t)N * 128;
  unsigned short* xh_bf  = usws + uoff; uoff += (size_t)N * 128;
  unsigned short* xw_bf  = usws + uoff; uoff += (size_t)N * 128;
  unsigned short* linWp  = usws + uoff; uoff += 128 * 128;
  unsigned short* convWp = usws + uoff; uoff += 3 * 128 * 128;
  unsigned short* Bi     = usws + uoff; uoff += 384 * 128;
  unsigned short* Bh     = usws + uoff; uoff += 384 * 128;

  // ---- weight packing ----
  // linW [128,128]: B[k][n] = linW[k][n]
  k_packB<<<(8 * 4 * 64 + 255) / 256, 256, 0, stream>>>(linW, linWp, 128, 128, 128, 0);
  // convW[l] [128,128]
  for (int l = 0; l < 3; ++l)
    k_packB<<<(8 * 4 * 64 + 255) / 256, 256, 0, stream>>>(
        convW + (size_t)l * 128 * 128, convWp + (size_t)l * 128 * 128, 128, 128, 128, 0);
  // Wih/Whh [384,128]: B[k][n] = W[n][k] -> trans
  k_packB<<<(24 * 4 * 64 + 255) / 256, 256, 0, stream>>>(Wih, Bi, 128, 384, 128, 1);
  k_packB<<<(24 * 4 * 64 + 255) / 256, 256, 0, stream>>>(Whh, Bh, 128, 384, 128, 1);

  // ---- x -> bf16 ----
  k_f2bf<<<(int)(((size_t)N * 16 + 255) / 256), 256, 0, stream>>>(x, x_bf, (size_t)N * 16);

  // ---- degree -> dinv ----
  k_fill1<<<nb, 256, 0, stream>>>(dinv, N);
  k_scatter_deg<<<(E + 255) / 256, 256, 0, stream>>>(dstI, ew, dinv, E);
  k_rsqrt<<<nb, 256, 0, stream>>>(dinv, N);

  // ---- CSR build ----
  k_zero_i<<<nb, 256, 0, stream>>>(cnt, N);
  k_count<<<(E + 255) / 256, 256, 0, stream>>>(dstI, cnt, E);
  k_scan_block<<<nb, 256, 0, stream>>>(cnt, partial, bsum, N);
  k_scan_sums<<<1, 512, 0, stream>>>(bsum, nb);
  k_scan_add<<<nb, 256, 0, stream>>>(partial, bsum, rowptr, cursor, N);
  k_csr_fill<<<(E + 255) / 256, 256, 0, stream>>>(
      srcI, dstI, ew, dinv, cursor, csr_src, csr_w, E);

  int gwave = (N + 63) / 64;  // 4 waves x 16 rows per block

  // xh = relu(x @ linW + linB)  [bf16 out]
  k_mfma_gemm<true, true><<<gwave, 256, 0, stream>>>(x_bf, linWp, linB, xh_bf, N);

  // GRU #1 (h0 -> h)
  k_gru_mfma<<<gwave, 256, 0, stream>>>(xh_bf, h0, h, Bi, Bh, bih, bhh, N);

  for (int l = 0; l < 3; ++l) {
    // xw = xh @ convW[l]
    k_mfma_gemm<false, false><<<gwave, 256, 0, stream>>>(
        xh_bf, convWp + (size_t)l * 128 * 128, nullptr, xw_bf, N);
    // xh = relu(gather(xw) + self-loop + bias)
    k_gather<<<(N + 1) / 2, 256, 0, stream>>>(
        rowptr, csr_src, csr_w, xw_bf, dinv, convB + (size_t)l * 128, xh_bf, N);
    // GRU (in-place h)
    k_gru_mfma<<<gwave, 256, 0, stream>>>(xh_bf, h, h, Bi, Bh, bih, bhh, N);
  }

  // out = h @ fcW + fcB (fp32)
  dim3 g40(1, (N + 63) / 64);
  k_gemm128<false, true><<<g40, 256, 0, stream>>>(h, fcW, fcB, (float*)d_out, N, 40);
}

// Round 5
// 1044.894 us; speedup vs baseline: 4.5059x; 1.5999x over previous
//
#include <hip/hip_runtime.h>
#include <hip/hip_bf16.h>
#include <math.h>

typedef __attribute__((ext_vector_type(8))) short bf8_t;   // 8 x bf16 (4 VGPRs)
typedef __attribute__((ext_vector_type(4))) float f4_t;    // MFMA accumulator
typedef __attribute__((ext_vector_type(8))) unsigned short us8_t;

__device__ inline unsigned short f2bf(float f) {
  union { float f; unsigned u; } x; x.f = f;
  unsigned r = x.u + 0x7FFF + ((x.u >> 16) & 1);   // RNE
  return (unsigned short)(r >> 16);
}
__device__ inline float bf2f(unsigned short b) {
  union { unsigned u; float f; } x; x.u = ((unsigned)b) << 16;
  return x.f;
}
// packed-pair helpers: lo/hi bf16 of a uint -> float
__device__ inline float bflo(unsigned v) {
  union { unsigned u; float f; } x; x.u = v << 16; return x.f;
}
__device__ inline float bfhi(unsigned v) {
  union { unsigned u; float f; } x; x.u = v & 0xFFFF0000u; return x.f;
}

// ---------------------------------------------------------------------------
// small utility kernels
// ---------------------------------------------------------------------------

__global__ void k_fill1(float* __restrict__ p, int n) {
  int i = blockIdx.x * blockDim.x + threadIdx.x;
  if (i < n) p[i] = 1.0f;
}

__global__ void k_zero_i(int* __restrict__ p, int n) {
  int i = blockIdx.x * blockDim.x + threadIdx.x;
  if (i < n) p[i] = 0;
}

__global__ void k_scatter_deg(const int* __restrict__ dst, const float* __restrict__ ew,
                              float* __restrict__ deg, int E) {
  int e = blockIdx.x * blockDim.x + threadIdx.x;
  if (e < E) atomicAdd(&deg[dst[e]], ew[e]);
}

__global__ void k_count(const int* __restrict__ dst, int* __restrict__ cnt, int E) {
  int e = blockIdx.x * blockDim.x + threadIdx.x;
  if (e < E) atomicAdd(&cnt[dst[e]], 1);
}

__global__ void k_rsqrt(float* __restrict__ p, int n) {
  int i = blockIdx.x * blockDim.x + threadIdx.x;
  if (i < n) p[i] = rsqrtf(p[i]);
}

// fp32 -> bf16 bulk convert (n multiple of 8)
__global__ void k_f2bf(const float* __restrict__ in, unsigned short* __restrict__ out,
                       size_t n8) {
  size_t i = (size_t)blockIdx.x * blockDim.x + threadIdx.x;
  if (i >= n8) return;
  const float4* p = (const float4*)(in + i * 8);
  float4 a = p[0], b = p[1];
  us8_t v;
  v[0] = f2bf(a.x); v[1] = f2bf(a.y); v[2] = f2bf(a.z); v[3] = f2bf(a.w);
  v[4] = f2bf(b.x); v[5] = f2bf(b.y); v[6] = f2bf(b.z); v[7] = f2bf(b.w);
  *(us8_t*)(out + i * 8) = v;
}

// pack weight matrix into MFMA B-fragment order (16x16x32 bf16).
// B[k][n] = trans ? W[n*ldw+k] : W[k*ldw+n]
// fragment (n0,k0): lane holds B[k0*32+(lane>>4)*8+j][n0*16+(lane&15)], j=0..7
__global__ void k_packB(const float* __restrict__ W, unsigned short* __restrict__ out,
                        int K, int Ncols, int ldw, int trans) {
  int idx = blockIdx.x * 256 + threadIdx.x;
  int total = (Ncols / 16) * (K / 32) * 64;
  if (idx >= total) return;
  int lane = idx & 63;
  int frag = idx >> 6;
  int kt = K / 32;
  int k0 = frag % kt;
  int n0 = frag / kt;
  int n = n0 * 16 + (lane & 15);
  int kbase = k0 * 32 + (lane >> 4) * 8;
  us8_t v;
#pragma unroll
  for (int j = 0; j < 8; ++j) {
    int k = kbase + j;
    float f = trans ? W[(size_t)n * ldw + k] : W[(size_t)k * ldw + n];
    v[j] = f2bf(f);
  }
  *(us8_t*)(out + (size_t)idx * 8) = v;
}

// ---------------------------------------------------------------------------
// hierarchical scan for rowptr (N up to 512*256 = 131072)
// ---------------------------------------------------------------------------

__global__ __launch_bounds__(256) void k_scan_block(
    const int* __restrict__ cnt, int* __restrict__ partial,
    int* __restrict__ bsum, int n) {
  __shared__ int s[256];
  int tid = threadIdx.x;
  int i = blockIdx.x * 256 + tid;
  s[tid] = (i < n) ? cnt[i] : 0;
  __syncthreads();
#pragma unroll
  for (int d = 1; d < 256; d <<= 1) {
    int t = (tid >= d) ? s[tid - d] : 0;
    __syncthreads();
    s[tid] += t;
    __syncthreads();
  }
  if (i < n) partial[i] = s[tid];
  if (tid == 255) bsum[blockIdx.x] = s[255];
}

__global__ __launch_bounds__(512) void k_scan_sums(int* __restrict__ bsum, int nb) {
  __shared__ int s[512];
  int tid = threadIdx.x;
  s[tid] = (tid < nb) ? bsum[tid] : 0;
  __syncthreads();
#pragma unroll
  for (int d = 1; d < 512; d <<= 1) {
    int t = (tid >= d) ? s[tid - d] : 0;
    __syncthreads();
    s[tid] += t;
    __syncthreads();
  }
  if (tid < nb) bsum[tid] = s[tid];
}

__global__ __launch_bounds__(256) void k_scan_add(
    const int* __restrict__ partial, const int* __restrict__ bsum,
    int* __restrict__ rowptr, int* __restrict__ cursor, int n) {
  int i = blockIdx.x * 256 + threadIdx.x;
  if (i == 0) { rowptr[0] = 0; cursor[0] = 0; }
  if (i < n) {
    int v = partial[i] + (blockIdx.x > 0 ? bsum[blockIdx.x - 1] : 0);
    rowptr[i + 1] = v;
    if (i + 1 < n) cursor[i + 1] = v;
  }
}

// scatter edges into CSR slots; record = (src, weight-bits) packed int2
__global__ __launch_bounds__(256) void k_csr_fill(
    const int* __restrict__ src, const int* __restrict__ dst,
    const float* __restrict__ ew, const float* __restrict__ dinv,
    int* __restrict__ cursor, int2* __restrict__ csr, int E) {
  int e = blockIdx.x * 256 + threadIdx.x;
  if (e >= E) return;
  int s = src[e], d = dst[e];
  float w = dinv[s] * ew[e] * dinv[d];
  int pos = atomicAdd(&cursor[d], 1);
  csr[pos] = make_int2(s, __float_as_int(w));
}

// ---------------------------------------------------------------------------
// MFMA GEMM: C[M,128] = A[M,128] @ B[128,128] (+bias)(+relu), bf16 in/out.
// ---------------------------------------------------------------------------

template<bool RELU, bool BIAS>
__global__ __launch_bounds__(256) void k_mfma_gemm(
    const unsigned short* __restrict__ A, const unsigned short* __restrict__ Bp,
    const float* __restrict__ bias, unsigned short* __restrict__ C, int M) {
  int wave = threadIdx.x >> 6, lane = threadIdx.x & 63;
  int row0 = (blockIdx.x * 4 + wave) * 16;
  if (row0 >= M) return;
  int m = lane & 15, q = lane >> 4;
  int arow = row0 + m; if (arow >= M) arow = M - 1;
  bf8_t a[4];
#pragma unroll
  for (int k0 = 0; k0 < 4; ++k0)
    a[k0] = *(const bf8_t*)(A + (size_t)arow * 128 + k0 * 32 + q * 8);
#pragma unroll
  for (int n0 = 0; n0 < 8; ++n0) {
    f4_t acc = {};
#pragma unroll
    for (int k0 = 0; k0 < 4; ++k0) {
      bf8_t b = *(const bf8_t*)(Bp + ((size_t)(n0 * 4 + k0) * 64 + lane) * 8);
      acc = __builtin_amdgcn_mfma_f32_16x16x32_bf16(a[k0], b, acc, 0, 0, 0);
    }
    int col = n0 * 16 + m;
    float bs = BIAS ? bias[col] : 0.f;
#pragma unroll
    for (int r = 0; r < 4; ++r) {
      int grow = row0 + q * 4 + r;
      if (grow < M) {
        float v = acc[r] + bs;
        if (RELU) v = fmaxf(v, 0.f);
        C[(size_t)grow * 128 + col] = f2bf(v);
      }
    }
  }
}

// ---------------------------------------------------------------------------
// Fused MFMA GRU. Wave owns 16 rows; in-place h safe.
// ---------------------------------------------------------------------------

__global__ __launch_bounds__(256) void k_gru_mfma(
    const unsigned short* __restrict__ xh,  // [M,128] bf16
    const float* h_in,                      // [M,128] fp32
    float* h_out,                           // [M,128] fp32 (may alias h_in)
    const unsigned short* __restrict__ Bi,  // packed WihT (K=128, Ncols=384)
    const unsigned short* __restrict__ Bh,  // packed WhhT
    const float* __restrict__ bih, const float* __restrict__ bhh, int M) {
  int wave = threadIdx.x >> 6, lane = threadIdx.x & 63;
  int row0 = (blockIdx.x * 4 + wave) * 16;
  if (row0 >= M) return;
  int m = lane & 15, q = lane >> 4;
  int arow = row0 + m; if (arow >= M) arow = M - 1;

  bf8_t ax[4], ah[4];
#pragma unroll
  for (int k0 = 0; k0 < 4; ++k0) {
    ax[k0] = *(const bf8_t*)(xh + (size_t)arow * 128 + k0 * 32 + q * 8);
    const float* hp = h_in + (size_t)arow * 128 + k0 * 32 + q * 8;
    float4 h0 = *(const float4*)hp;
    float4 h1 = *(const float4*)(hp + 4);
    bf8_t t;
    t[0] = (short)f2bf(h0.x); t[1] = (short)f2bf(h0.y);
    t[2] = (short)f2bf(h0.z); t[3] = (short)f2bf(h0.w);
    t[4] = (short)f2bf(h1.x); t[5] = (short)f2bf(h1.y);
    t[6] = (short)f2bf(h1.z); t[7] = (short)f2bf(h1.w);
    ah[k0] = t;
  }

  for (int g = 0; g < 8; ++g) {
    f4_t air = {}, aiz = {}, ain = {}, ahr = {}, ahz = {}, ahn = {};
#pragma unroll
    for (int k0 = 0; k0 < 4; ++k0) {
      bf8_t br = *(const bf8_t*)(Bi + ((size_t)((g     ) * 4 + k0) * 64 + lane) * 8);
      bf8_t bz = *(const bf8_t*)(Bi + ((size_t)((g +  8) * 4 + k0) * 64 + lane) * 8);
      bf8_t bn = *(const bf8_t*)(Bi + ((size_t)((g + 16) * 4 + k0) * 64 + lane) * 8);
      air = __builtin_amdgcn_mfma_f32_16x16x32_bf16(ax[k0], br, air, 0, 0, 0);
      aiz = __builtin_amdgcn_mfma_f32_16x16x32_bf16(ax[k0], bz, aiz, 0, 0, 0);
      ain = __builtin_amdgcn_mfma_f32_16x16x32_bf16(ax[k0], bn, ain, 0, 0, 0);
      bf8_t cr = *(const bf8_t*)(Bh + ((size_t)((g     ) * 4 + k0) * 64 + lane) * 8);
      bf8_t cz = *(const bf8_t*)(Bh + ((size_t)((g +  8) * 4 + k0) * 64 + lane) * 8);
      bf8_t cn = *(const bf8_t*)(Bh + ((size_t)((g + 16) * 4 + k0) * 64 + lane) * 8);
      ahr = __builtin_amdgcn_mfma_f32_16x16x32_bf16(ah[k0], cr, ahr, 0, 0, 0);
      ahz = __builtin_amdgcn_mfma_f32_16x16x32_bf16(ah[k0], cz, ahz, 0, 0, 0);
      ahn = __builtin_amdgcn_mfma_f32_16x16x32_bf16(ah[k0], cn, ahn, 0, 0, 0);
    }
    int col = g * 16 + m;
    float bir_ = bih[col], biz_ = bih[col + 128], bin_ = bih[col + 256];
    float bhr_ = bhh[col], bhz_ = bhh[col + 128], bhn_ = bhh[col + 256];
#pragma unroll
    for (int r = 0; r < 4; ++r) {
      int grow = row0 + q * 4 + r;
      if (grow < M) {
        float hprev = h_in[(size_t)grow * 128 + col];
        float rr = 1.f / (1.f + expf(-(air[r] + bir_ + ahr[r] + bhr_)));
        float zz = 1.f / (1.f + expf(-(aiz[r] + biz_ + ahz[r] + bhz_)));
        float nn = tanhf(ain[r] + bin_ + rr * (ahn[r] + bhn_));
        h_out[(size_t)grow * 128 + col] = (1.f - zz) * nn + zz * hprev;
      }
    }
  }
}

// ---------------------------------------------------------------------------
// fp32 GEMM (final fc layer)
// ---------------------------------------------------------------------------

template<bool RELU, bool BIAS>
__global__ __launch_bounds__(256) void k_gemm128(
    const float* __restrict__ A, const float* __restrict__ B,
    const float* __restrict__ bias, float* __restrict__ C, int M, int Nc) {
  __shared__ float As[64][36];
  __shared__ float Bs[32][64];
  int tid = threadIdx.x;
  int tx = tid & 15, ty = tid >> 4;
  int row0 = blockIdx.y * 64, col0 = blockIdx.x * 64;
  float acc[4][4] = {};

  for (int k0 = 0; k0 < 128; k0 += 32) {
#pragma unroll
    for (int i = 0; i < 2; ++i) {
      int f = tid + i * 256;
      int r = f >> 3, c4 = f & 7;
      int gr = row0 + r;
      float4 v = make_float4(0.f, 0.f, 0.f, 0.f);
      if (gr < M) v = *(const float4*)(A + (size_t)gr * 128 + k0 + c4 * 4);
      *(float4*)(&As[r][c4 * 4]) = v;
    }
#pragma unroll
    for (int i = 0; i < 2; ++i) {
      int f = tid + i * 256;
      int r = f >> 4, c4 = f & 15;
      int gc = col0 + c4 * 4;
      float4 v = make_float4(0.f, 0.f, 0.f, 0.f);
      if (gc + 3 < Nc) v = *(const float4*)(B + (size_t)(k0 + r) * Nc + gc);
      *(float4*)(&Bs[r][c4 * 4]) = v;
    }
    __syncthreads();
#pragma unroll
    for (int kk = 0; kk < 32; ++kk) {
      float4 b = *(float4*)(&Bs[kk][tx * 4]);
      float a0 = As[ty * 4 + 0][kk];
      float a1 = As[ty * 4 + 1][kk];
      float a2 = As[ty * 4 + 2][kk];
      float a3 = As[ty * 4 + 3][kk];
      acc[0][0] += a0 * b.x; acc[0][1] += a0 * b.y; acc[0][2] += a0 * b.z; acc[0][3] += a0 * b.w;
      acc[1][0] += a1 * b.x; acc[1][1] += a1 * b.y; acc[1][2] += a1 * b.z; acc[1][3] += a1 * b.w;
      acc[2][0] += a2 * b.x; acc[2][1] += a2 * b.y; acc[2][2] += a2 * b.z; acc[2][3] += a2 * b.w;
      acc[3][0] += a3 * b.x; acc[3][1] += a3 * b.y; acc[3][2] += a3 * b.z; acc[3][3] += a3 * b.w;
    }
    __syncthreads();
  }

#pragma unroll
  for (int i = 0; i < 4; ++i) {
    int gr = row0 + ty * 4 + i;
    if (gr >= M) continue;
#pragma unroll
    for (int j = 0; j < 4; ++j) {
      int gc = col0 + tx * 4 + j;
      if (gc >= Nc) continue;
      float v = acc[i][j];
      if (BIAS) v += bias[gc];
      if (RELU) v = fmaxf(v, 0.f);
      C[(size_t)gr * Nc + gc] = v;
    }
  }
}

// ---------------------------------------------------------------------------
// CSR gather aggregation: 1 node per wave, lane owns 2 channels (packed uint).
// Edge records are wave-uniform (scalar loads); 4x unrolled for MLP.
//   out[i,:] = relu( sum_e xw[src_e,:]*w_e + xw[i,:]*dinv_i^2 + bias )
// ---------------------------------------------------------------------------

__global__ __launch_bounds__(256) void k_gather(
    const int* __restrict__ rowptr, const int2* __restrict__ csr,
    const unsigned* __restrict__ xw,   // [N,64] packed bf16x2
    const float* __restrict__ dinv, const float* __restrict__ bias,
    unsigned* __restrict__ out, int N) {
  int wave = threadIdx.x >> 6;
  int lane = threadIdx.x & 63;
  int node = __builtin_amdgcn_readfirstlane(blockIdx.x * 4 + wave);
  if (node >= N) return;
  int beg = __builtin_amdgcn_readfirstlane(rowptr[node]);
  int end = __builtin_amdgcn_readfirstlane(rowptr[node + 1]);

  float accl = 0.f, acch = 0.f;
  int k = beg;
  for (; k + 4 <= end; k += 4) {
    int2 e0 = csr[k], e1 = csr[k + 1], e2 = csr[k + 2], e3 = csr[k + 3];
    unsigned v0 = xw[((size_t)e0.x << 6) + lane];
    unsigned v1 = xw[((size_t)e1.x << 6) + lane];
    unsigned v2 = xw[((size_t)e2.x << 6) + lane];
    unsigned v3 = xw[((size_t)e3.x << 6) + lane];
    float w0 = __int_as_float(e0.y), w1 = __int_as_float(e1.y);
    float w2 = __int_as_float(e2.y), w3 = __int_as_float(e3.y);
    accl += bflo(v0) * w0; acch += bfhi(v0) * w0;
    accl += bflo(v1) * w1; acch += bfhi(v1) * w1;
    accl += bflo(v2) * w2; acch += bfhi(v2) * w2;
    accl += bflo(v3) * w3; acch += bfhi(v3) * w3;
  }
  for (; k < end; ++k) {
    int2 e = csr[k];
    unsigned v = xw[((size_t)e.x << 6) + lane];
    float w = __int_as_float(e.y);
    accl += bflo(v) * w; acch += bfhi(v) * w;
  }

  float di = dinv[node];
  float sn = di * di;
  unsigned vs = xw[((size_t)node << 6) + lane];
  float2 b = *(const float2*)(bias + lane * 2);
  float rl = fmaxf(accl + bflo(vs) * sn + b.x, 0.f);
  float rh = fmaxf(acch + bfhi(vs) * sn + b.y, 0.f);
  unsigned o = (unsigned)f2bf(rl) | ((unsigned)f2bf(rh) << 16);
  out[((size_t)node << 6) + lane] = o;
}

// ---------------------------------------------------------------------------

extern "C" void kernel_launch(void* const* d_in, const int* in_sizes, int n_in,
                              void* d_out, int out_size, void* d_ws, size_t ws_size,
                              hipStream_t stream) {
  const float* x    = (const float*)d_in[0];
  const int*   ei   = (const int*)d_in[1];
  const float* ew   = (const float*)d_in[2];
  const float* h0   = (const float*)d_in[3];
  const float* linW = (const float*)d_in[4];
  const float* linB = (const float*)d_in[5];
  const float* convW= (const float*)d_in[6];
  const float* convB= (const float*)d_in[7];
  const float* Wih  = (const float*)d_in[8];
  const float* Whh  = (const float*)d_in[9];
  const float* bih  = (const float*)d_in[10];
  const float* bhh  = (const float*)d_in[11];
  const float* fcW  = (const float*)d_in[12];
  const float* fcB  = (const float*)d_in[13];

  int N = in_sizes[0] / 128;
  int E = in_sizes[1] / 2;
  const int* srcI = ei;
  const int* dstI = ei + E;
  int nb = (N + 255) / 256;

  // ---- workspace layout ----
  float* ws = (float*)d_ws;
  size_t off = 0;
  float* dinv = ws + off; off += (size_t)N;
  if (off & 1) off++;                       // 8B-align what follows
  float* h    = ws + off; off += (size_t)N * 128;
  int* iws = (int*)(ws + off);              // 8B-aligned
  size_t ioff = 0;
  int2* csr    = (int2*)iws; ioff += (size_t)2 * E;
  int* cnt     = iws + ioff; ioff += (size_t)N;
  int* partial = iws + ioff; ioff += (size_t)N;
  int* bsum    = iws + ioff; ioff += 512;
  int* rowptr  = iws + ioff; ioff += (size_t)N + 1;
  int* cursor  = iws + ioff; ioff += (size_t)N;
  ioff = (ioff + 3) & ~(size_t)3;           // 16B-align ushort area
  unsigned short* usws = (unsigned short*)(iws + ioff);
  size_t uoff = 0;
  unsigned short* x_bf   = usws + uoff; uoff += (size_t)N * 128;
  unsigned short* xh_bf  = usws + uoff; uoff += (size_t)N * 128;
  unsigned short* xw_bf  = usws + uoff; uoff += (size_t)N * 128;
  unsigned short* linWp  = usws + uoff; uoff += 128 * 128;
  unsigned short* convWp = usws + uoff; uoff += 3 * 128 * 128;
  unsigned short* Bi     = usws + uoff; uoff += 384 * 128;
  unsigned short* Bh     = usws + uoff; uoff += 384 * 128;

  // ---- weight packing ----
  k_packB<<<(8 * 4 * 64 + 255) / 256, 256, 0, stream>>>(linW, linWp, 128, 128, 128, 0);
  for (int l = 0; l < 3; ++l)
    k_packB<<<(8 * 4 * 64 + 255) / 256, 256, 0, stream>>>(
        convW + (size_t)l * 128 * 128, convWp + (size_t)l * 128 * 128, 128, 128, 128, 0);
  k_packB<<<(24 * 4 * 64 + 255) / 256, 256, 0, stream>>>(Wih, Bi, 128, 384, 128, 1);
  k_packB<<<(24 * 4 * 64 + 255) / 256, 256, 0, stream>>>(Whh, Bh, 128, 384, 128, 1);

  // ---- x -> bf16 ----
  k_f2bf<<<(int)(((size_t)N * 16 + 255) / 256), 256, 0, stream>>>(x, x_bf, (size_t)N * 16);

  // ---- degree -> dinv ----
  k_fill1<<<nb, 256, 0, stream>>>(dinv, N);
  k_scatter_deg<<<(E + 255) / 256, 256, 0, stream>>>(dstI, ew, dinv, E);
  k_rsqrt<<<nb, 256, 0, stream>>>(dinv, N);

  // ---- CSR build ----
  k_zero_i<<<nb, 256, 0, stream>>>(cnt, N);
  k_count<<<(E + 255) / 256, 256, 0, stream>>>(dstI, cnt, E);
  k_scan_block<<<nb, 256, 0, stream>>>(cnt, partial, bsum, N);
  k_scan_sums<<<1, 512, 0, stream>>>(bsum, nb);
  k_scan_add<<<nb, 256, 0, stream>>>(partial, bsum, rowptr, cursor, N);
  k_csr_fill<<<(E + 255) / 256, 256, 0, stream>>>(
      srcI, dstI, ew, dinv, cursor, csr, E);

  int gwave = (N + 63) / 64;  // 4 waves x 16 rows per block

  // xh = relu(x @ linW + linB)  [bf16 out]
  k_mfma_gemm<true, true><<<gwave, 256, 0, stream>>>(x_bf, linWp, linB, xh_bf, N);

  // GRU #1 (h0 -> h)
  k_gru_mfma<<<gwave, 256, 0, stream>>>(xh_bf, h0, h, Bi, Bh, bih, bhh, N);

  int ggat = (N + 3) / 4;     // 1 node per wave, 4 waves/block
  for (int l = 0; l < 3; ++l) {
    k_mfma_gemm<false, false><<<gwave, 256, 0, stream>>>(
        xh_bf, convWp + (size_t)l * 128 * 128, nullptr, xw_bf, N);
    k_gather<<<ggat, 256, 0, stream>>>(
        rowptr, csr, (const unsigned*)xw_bf, dinv, convB + (size_t)l * 128,
        (unsigned*)xh_bf, N);
    k_gru_mfma<<<gwave, 256, 0, stream>>>(xh_bf, h, h, Bi, Bh, bih, bhh, N);
  }

  // out = h @ fcW + fcB (fp32)
  dim3 g40(1, (N + 63) / 64);
  k_gemm128<false, true><<<g40, 256, 0, stream>>>(h, fcW, fcB, (float*)d_out, N, 40);
}